// Round 9
// baseline (833.733 us; speedup 1.0000x reference)
//
#include <hip/hip_runtime.h>
#include <math.h>

// ChamferLoss on MI355X — round 9: fast-path 3x3x3 query + fused scan.
// Round 8 (wave-per-query): 670 µs total = 401 query + 269 aux. This round:
//  (a) query: fused 3x3x3 window (9 contiguous rows, uniform offsets
//      prefetched via SGPR loads, ONE reduce + ONE bound check) — density
//      says ~all queries terminate at Chebyshev radius 1; general shell
//      loop kept from s=2 for exactness.
//  (b) scan1+scan2+scan3 -> one single-block scan kernel (7 dispatches vs 9).
// Bin/fill math identical to the PASSING rounds 7/8.

#define N_PTS 147456          // 384*384
#define N2    (2 * N_PTS)     // both clouds
#define IMG_W 384
#define G     48              // grid edge
#define NC    (G * G * G)     // 110592 cells per cloud
#define NCI   (2 * NC)        // 221184 cells total
#define SCALE 0.48f           // cells per meter: (x+50)*SCALE in [0,48)
#define HC    2.0833333f      // cell width lower bound (conservative)
#define ZERO_BLOCKS 864       // NCI / 256

// ---- shared geometry (count & fill & query must agree exactly) ----

__device__ __forceinline__ float4 transform_pt(
    int idx, const float* __restrict__ fake, const float* __restrict__ tar,
    int sh, int sw)
{
    int pix = (idx < N_PTS) ? idx : idx - N_PTS;
    int r = pix / IMG_W, c = pix - r * IMG_W;
    float cw = (float)((double)sw / 1285.0 * 360.0);
    float ch = (float)((double)sh / 438.0 * 123.5);
    const float fh = (float)(360.0 * 384.0 / 1285.0);   // fh_crop
    const float fv = (float)(123.5 * 384.0 / 438.0);    // fv_crop
    const float D2R = 0.017453292519943295f;
    float yaw = ((-fh * (float)c) / 384.0f + cw) * D2R;
    float pit = ((-fv * (float)r) / 384.0f + ch) * D2R;
    float sy = sinf(yaw), cy = cosf(yaw);
    float sp = sinf(pit), cp = cosf(pit);
    float d = (idx < N_PTS) ? tar[pix] : fake[pix];   // A=transform(tar), B=transform(fake)
    return make_float4(d * sy * sp, d * cy * sp, d * cp, 0.f);
}

__device__ __forceinline__ int cell_coord(float v) {
    int c = (int)((v + 50.0f) * SCALE);
    return min(max(c, 0), G - 1);
}

__device__ __forceinline__ int cell_of(float x, float y, float z) {
    return (cell_coord(z) * G + cell_coord(y)) * G + cell_coord(x);
}

// ---- pipeline ----

__global__ __launch_bounds__(256) void zero_kernel(int* __restrict__ p) {
    p[blockIdx.x * 256 + threadIdx.x] = 0;   // grid = ZERO_BLOCKS covers NCI
}

__global__ __launch_bounds__(256) void count_kernel(
    const float* __restrict__ fake, const float* __restrict__ tar,
    const int* __restrict__ sh_p, const int* __restrict__ sw_p,
    int* __restrict__ offc)
{
    int idx = blockIdx.x * 256 + threadIdx.x;    // grid = N2/256
    float4 p = transform_pt(idx, fake, tar, *sh_p, *sw_p);
    int bucket = ((idx < N_PTS) ? 0 : NC) + cell_of(p.x, p.y, p.z);
    atomicAdd(&offc[bucket], 1);
}

// Single-block exclusive scan of offc[NCI] in place. 1024 threads x 216 cells.
__global__ __launch_bounds__(1024) void scan_kernel(int* __restrict__ offc)
{
    __shared__ int sums[1024];
    const int t = threadIdx.x;
    const int CPT = NCI / 1024;            // 216
    const int base = t * CPT;
    int s = 0;
    #pragma unroll 8
    for (int i = 0; i < CPT; i++) s += offc[base + i];
    sums[t] = s;
    __syncthreads();
    for (int o = 1; o < 1024; o <<= 1) {   // Hillis-Steele inclusive
        int v = (t >= o) ? sums[t - o] : 0;
        __syncthreads();
        sums[t] += v;
        __syncthreads();
    }
    int run = sums[t] - s;                 // exclusive prefix of this chunk
    for (int i = 0; i < CPT; i++) {
        int c = offc[base + i];
        offc[base + i] = run;
        run += c;
    }
}

// scatter points into CSR slots; afterwards offc[c] = END offset of cell c
__global__ __launch_bounds__(256) void fill_kernel(
    const float* __restrict__ fake, const float* __restrict__ tar,
    const int* __restrict__ sh_p, const int* __restrict__ sw_p,
    int* __restrict__ offc, float4* __restrict__ pts)
{
    int idx = blockIdx.x * 256 + threadIdx.x;
    float4 p = transform_pt(idx, fake, tar, *sh_p, *sw_p);
    int bucket = ((idx < N_PTS) ? 0 : NC) + cell_of(p.x, p.y, p.z);
    int slot = atomicAdd(&offc[bucket], 1);
    pts[slot] = make_float4(p.x, p.y, p.z, 0.f);
}

// WAVE-PER-QUERY exact NN: fused 3x3x3 fast window, shells from s=2 if needed.
// CSR range of cells [c0..c1]: [ c0 ? offc[c0-1] : 0 , offc[c1] ).
__global__ __launch_bounds__(256) void query_kernel(
    float4* __restrict__ pts, const int* __restrict__ offc)
{
    const int lane = threadIdx.x & 63;
    const int g = blockIdx.x * 4 + (threadIdx.x >> 6);   // query slot, one/wave
    float4 q = pts[g];                                    // broadcast load
    const float qx = q.x, qy = q.y, qz = q.z;
    const int base = __builtin_amdgcn_readfirstlane((g < N_PTS) ? NC : 0);

    // wave-uniform cell coords in SGPRs
    const int cx = __builtin_amdgcn_readfirstlane(cell_coord(qx));
    const int cy = __builtin_amdgcn_readfirstlane(cell_coord(qy));
    const int cz = __builtin_amdgcn_readfirstlane(cell_coord(qz));
    float fx = (qx + 50.0f) * SCALE - (float)cx;
    float fy = (qy + 50.0f) * SCALE - (float)cy;
    float fz = (qz + 50.0f) * SCALE - (float)cz;
    float m = fmaxf(fminf(fminf(fminf(fx, 1.0f - fx), fminf(fy, 1.0f - fy)),
                          fminf(fz, 1.0f - fz)), 0.0f);

    const int xlo = max(cx - 1, 0), xhi = min(cx + 1, G - 1);

    // prefetch the 9 row ranges of the 3x3x3 window (uniform addresses)
    int lo9[9], hi9[9];
    #pragma unroll
    for (int dz = 0; dz < 3; dz++) {
        #pragma unroll
        for (int dy = 0; dy < 3; dy++) {
            int iz = cz + dz - 1, iy = cy + dy - 1;
            bool ok = (iz >= 0) && (iz < G) && (iy >= 0) && (iy < G);
            int rowb = ok ? (base + (iz * G + iy) * G) : base;  // safe addr
            int c0 = rowb + xlo, c1 = rowb + xhi;
            int l = c0 ? offc[c0 - 1] : 0;
            int h = offc[c1];
            lo9[dz * 3 + dy] = l;
            hi9[dz * 3 + dy] = ok ? h : l;                      // empty if invalid
        }
    }

    float best = __builtin_inff();
    #pragma unroll
    for (int i = 0; i < 9; i++) {
        for (int j = lo9[i] + lane; j < hi9[i]; j += 64) {
            float4 t = pts[j];
            float ddx = t.x - qx, ddy = t.y - qy, ddz = t.z - qz;
            best = fminf(best, fmaf(ddx, ddx, fmaf(ddy, ddy, ddz * ddz)));
        }
    }
    #pragma unroll
    for (int o = 32; o; o >>= 1) best = fminf(best, __shfl_xor(best, o, 64));

    // all unscanned points are >= (1 + m) cell-widths away (conservative)
    float bnd1 = (1.0f + m) * HC;
    if (best > bnd1 * bnd1) {
        // rare: expand shells from s=2 (exact, as round 8)
        for (int s = 2; s <= G; ++s) {
            int zlo = max(cz - s, 0), zhi = min(cz + s, G - 1);
            for (int iz = zlo; iz <= zhi; ++iz) {
                int adz = iz - cz; adz = (adz < 0) ? -adz : adz;
                int ylo = max(cy - s, 0), yhi = min(cy + s, G - 1);
                for (int iy = ylo; iy <= yhi; ++iy) {
                    int ady = iy - cy; ady = (ady < 0) ? -ady : ady;
                    int rowb = base + (iz * G + iy) * G;
                    if (adz == s || ady == s) {        // full row of the shell
                        int c0 = rowb + max(cx - s, 0);
                        int c1 = rowb + min(cx + s, G - 1);
                        int lo = c0 ? offc[c0 - 1] : 0;
                        int hi = offc[c1];
                        for (int j = lo + lane; j < hi; j += 64) {
                            float4 t = pts[j];
                            float ddx = t.x - qx, ddy = t.y - qy, ddz = t.z - qz;
                            best = fminf(best, fmaf(ddx, ddx, fmaf(ddy, ddy, ddz * ddz)));
                        }
                    } else {                            // interior row: two end cells
                        if (cx - s >= 0) {
                            int c0 = rowb + cx - s;
                            int lo = c0 ? offc[c0 - 1] : 0;
                            int hi = offc[c0];
                            for (int j = lo + lane; j < hi; j += 64) {
                                float4 t = pts[j];
                                float ddx = t.x - qx, ddy = t.y - qy, ddz = t.z - qz;
                                best = fminf(best, fmaf(ddx, ddx, fmaf(ddy, ddy, ddz * ddz)));
                            }
                        }
                        if (cx + s <= G - 1) {
                            int c0 = rowb + cx + s;
                            int lo = c0 ? offc[c0 - 1] : 0;
                            int hi = offc[c0];
                            for (int j = lo + lane; j < hi; j += 64) {
                                float4 t = pts[j];
                                float ddx = t.x - qx, ddy = t.y - qy, ddz = t.z - qz;
                                best = fminf(best, fmaf(ddx, ddx, fmaf(ddy, ddy, ddz * ddz)));
                            }
                        }
                    }
                }
            }
            #pragma unroll
            for (int o = 32; o; o >>= 1) best = fminf(best, __shfl_xor(best, o, 64));
            float bnd = ((float)s + m) * HC;
            if (best <= bnd * bnd) break;
        }
    }

    if (lane == 0) pts[g].w = best;   // readers consume xyz only
}

// deterministic sum of pts[*].w
__global__ __launch_bounds__(256) void reduce1(
    const float4* __restrict__ pts, float* __restrict__ partials)
{
    int tid = threadIdx.x;
    int basei = blockIdx.x * 1024;
    float s = 0.f;
    #pragma unroll
    for (int t = 0; t < 4; t++) s += pts[basei + t * 256 + tid].w;
    #pragma unroll
    for (int o = 32; o; o >>= 1) s += __shfl_xor(s, o, 64);
    __shared__ float wsum[4];
    if ((tid & 63) == 0) wsum[tid >> 6] = s;
    __syncthreads();
    if (tid == 0) partials[blockIdx.x] = wsum[0] + wsum[1] + wsum[2] + wsum[3];
}

__global__ __launch_bounds__(256) void reduce2(
    const float* __restrict__ partials, float* __restrict__ out)
{
    int tid = threadIdx.x;
    float s = 0.f;
    for (int i = tid; i < 288; i += 256) s += partials[i];
    #pragma unroll
    for (int o = 32; o; o >>= 1) s += __shfl_xor(s, o, 64);
    __shared__ float wsum[4];
    if ((tid & 63) == 0) wsum[tid >> 6] = s;
    __syncthreads();
    if (tid == 0) out[0] = (wsum[0] + wsum[1] + wsum[2] + wsum[3]) / 147456.0f;
}

extern "C" void kernel_launch(void* const* d_in, const int* in_sizes, int n_in,
                              void* d_out, int out_size, void* d_ws, size_t ws_size,
                              hipStream_t stream) {
    const float* fake = (const float*)d_in[0];
    const float* tar  = (const float*)d_in[1];
    const int*   sh_p = (const int*)d_in[2];
    const int*   sw_p = (const int*)d_in[3];
    float* out = (float*)d_out;

    // ws layout identical to passing rounds 7/8: 5.35 MB total
    int* wsi = (int*)d_ws;
    int*    offc  = wsi;                        // NCI ints
    //      (bsum slot unused this round)       // 1024 ints, kept for layout
    float*  parts = (float*)(wsi + NCI + 1024); // 288 floats
    float4* pts   = (float4*)(wsi + NCI + 1312);// N2 float4, 16B-aligned

    zero_kernel<<<ZERO_BLOCKS, 256, 0, stream>>>(offc);
    count_kernel<<<N2 / 256, 256, 0, stream>>>(fake, tar, sh_p, sw_p, offc);
    scan_kernel<<<1, 1024, 0, stream>>>(offc);
    fill_kernel<<<N2 / 256, 256, 0, stream>>>(fake, tar, sh_p, sw_p, offc, pts);
    query_kernel<<<N2 / 4, 256, 0, stream>>>(pts, offc);   // one wave per query
    reduce1<<<N2 / 1024, 256, 0, stream>>>(pts, parts);
    reduce2<<<1, 256, 0, stream>>>(parts, out);
}

// Round 11
// 455.183 us; speedup vs baseline: 1.8316x; 1.8316x over previous
//
#include <hip/hip_runtime.h>
#include <math.h>

// ChamferLoss on MI355X — round 10 kernel (resubmit; round-10 bench was an
// infra failure, never measured).
// r8 (670 µs) beat r9 (834): the s=0 early-exit matters, and the single-block
// scan was uncoalesced. This round keeps r8's proven pipeline verbatim and
// attacks the candidate count: after the home-cell scan, each s=1 row segment
// is scanned ONLY if its geometric lower bound beats the wave-uniform best.
// Pruning uses the reduced (uniform) bestU -> no exec-mask fracture; skip is
// provably safe (lb <= true dist of every point in the row).

#define N_PTS 147456          // 384*384
#define N2    (2 * N_PTS)     // both clouds
#define IMG_W 384
#define G     48              // grid edge
#define NC    (G * G * G)     // 110592 cells per cloud
#define NCI   (2 * NC)        // 221184 cells total
#define SCALE 0.48f           // cells per meter: (x+50)*SCALE in [0,48)
#define HC    2.0833333f      // cell width lower bound (conservative)
#define SCAN_BLOCKS 864       // NCI / 256

// ---- shared geometry (count & fill & query must agree exactly) ----

__device__ __forceinline__ float4 transform_pt(
    int idx, const float* __restrict__ fake, const float* __restrict__ tar,
    int sh, int sw)
{
    int pix = (idx < N_PTS) ? idx : idx - N_PTS;
    int r = pix / IMG_W, c = pix - r * IMG_W;
    float cw = (float)((double)sw / 1285.0 * 360.0);
    float ch = (float)((double)sh / 438.0 * 123.5);
    const float fh = (float)(360.0 * 384.0 / 1285.0);   // fh_crop
    const float fv = (float)(123.5 * 384.0 / 438.0);    // fv_crop
    const float D2R = 0.017453292519943295f;
    float yaw = ((-fh * (float)c) / 384.0f + cw) * D2R;
    float pit = ((-fv * (float)r) / 384.0f + ch) * D2R;
    float sy = sinf(yaw), cy = cosf(yaw);
    float sp = sinf(pit), cp = cosf(pit);
    float d = (idx < N_PTS) ? tar[pix] : fake[pix];   // A=transform(tar), B=transform(fake)
    return make_float4(d * sy * sp, d * cy * sp, d * cp, 0.f);
}

__device__ __forceinline__ int cell_coord(float v) {
    int c = (int)((v + 50.0f) * SCALE);
    return min(max(c, 0), G - 1);
}

__device__ __forceinline__ int cell_of(float x, float y, float z) {
    return (cell_coord(z) * G + cell_coord(y)) * G + cell_coord(x);
}

// ---- pipeline (zero/count/scan1-3/fill identical to passing round 8) ----

__global__ __launch_bounds__(256) void zero_kernel(int* __restrict__ p) {
    p[blockIdx.x * 256 + threadIdx.x] = 0;
}

__global__ __launch_bounds__(256) void count_kernel(
    const float* __restrict__ fake, const float* __restrict__ tar,
    const int* __restrict__ sh_p, const int* __restrict__ sw_p,
    int* __restrict__ offc)
{
    int idx = blockIdx.x * 256 + threadIdx.x;
    float4 p = transform_pt(idx, fake, tar, *sh_p, *sw_p);
    int bucket = ((idx < N_PTS) ? 0 : NC) + cell_of(p.x, p.y, p.z);
    atomicAdd(&offc[bucket], 1);
}

__global__ __launch_bounds__(256) void scan1_kernel(
    int* __restrict__ offc, int* __restrict__ bsum)
{
    __shared__ int sd[256];
    int t = threadIdx.x;
    int gid = blockIdx.x * 256 + t;
    int c = offc[gid];
    sd[t] = c;
    __syncthreads();
    for (int o = 1; o < 256; o <<= 1) {
        int v = (t >= o) ? sd[t - o] : 0;
        __syncthreads();
        sd[t] += v;
        __syncthreads();
    }
    offc[gid] = sd[t] - c;
    if (t == 255) bsum[blockIdx.x] = sd[255];
}

__global__ __launch_bounds__(1024) void scan2_kernel(int* __restrict__ bsum)
{
    __shared__ int sd[1024];
    int t = threadIdx.x;
    int v0 = (t < SCAN_BLOCKS) ? bsum[t] : 0;
    sd[t] = v0;
    __syncthreads();
    for (int o = 1; o < 1024; o <<= 1) {
        int v = (t >= o) ? sd[t - o] : 0;
        __syncthreads();
        sd[t] += v;
        __syncthreads();
    }
    if (t < SCAN_BLOCKS) bsum[t] = sd[t] - v0;
}

__global__ __launch_bounds__(256) void scan3_kernel(
    int* __restrict__ offc, const int* __restrict__ bsum)
{
    int gid = blockIdx.x * 256 + threadIdx.x;
    offc[gid] += bsum[blockIdx.x];
}

__global__ __launch_bounds__(256) void fill_kernel(
    const float* __restrict__ fake, const float* __restrict__ tar,
    const int* __restrict__ sh_p, const int* __restrict__ sw_p,
    int* __restrict__ offc, float4* __restrict__ pts)
{
    int idx = blockIdx.x * 256 + threadIdx.x;
    float4 p = transform_pt(idx, fake, tar, *sh_p, *sw_p);
    int bucket = ((idx < N_PTS) ? 0 : NC) + cell_of(p.x, p.y, p.z);
    int slot = atomicAdd(&offc[bucket], 1);
    pts[slot] = make_float4(p.x, p.y, p.z, 0.f);
}

// candidate scan over CSR range [LO,HI): 64-lane stride, lane-local best
#define SCAN_RANGE(LO, HI)                                                  \
    for (int j = (LO) + lane; j < (HI); j += 64) {                          \
        float4 t = pts[j];                                                  \
        float ddx = t.x - qx, ddy = t.y - qy, ddz = t.z - qz;               \
        best = fminf(best, fmaf(ddx, ddx, fmaf(ddy, ddy, ddz * ddz)));      \
    }

#define WAVE_MIN(B)                                                         \
    _Pragma("unroll")                                                       \
    for (int o = 32; o; o >>= 1) (B) = fminf((B), __shfl_xor((B), o, 64));

// WAVE-PER-QUERY exact NN: home cell -> s=0 exit -> lb-pruned s=1 ->
// (1+m) exit -> generic shells (round-8 code) for the rare remainder.
__global__ __launch_bounds__(256) void query_kernel(
    float4* __restrict__ pts, const int* __restrict__ offc)
{
    const int lane = threadIdx.x & 63;
    const int g = blockIdx.x * 4 + (threadIdx.x >> 6);   // query slot, one/wave
    float4 q = pts[g];                                    // broadcast load
    const float qx = q.x, qy = q.y, qz = q.z;
    const int base = __builtin_amdgcn_readfirstlane((g < N_PTS) ? NC : 0);

    const int cx = __builtin_amdgcn_readfirstlane(cell_coord(qx));
    const int cy = __builtin_amdgcn_readfirstlane(cell_coord(qy));
    const int cz = __builtin_amdgcn_readfirstlane(cell_coord(qz));
    float fx = (qx + 50.0f) * SCALE - (float)cx;          // in [0,1)
    float fy = (qy + 50.0f) * SCALE - (float)cy;
    float fz = (qz + 50.0f) * SCALE - (float)cz;
    float m = fmaxf(fminf(fminf(fminf(fx, 1.0f - fx), fminf(fy, 1.0f - fy)),
                          fminf(fz, 1.0f - fz)), 0.0f);

    float best = __builtin_inff();

    // --- home cell ---
    {
        int c0 = base + (cz * G + cy) * G + cx;
        int lo = c0 ? offc[c0 - 1] : 0;
        int hi = offc[c0];
        SCAN_RANGE(lo, hi)
    }
    WAVE_MIN(best)
    float m2 = m * HC;
    if (best > m2 * m2) {
        // --- s=1: 8 full rows + 2 end cells, each lb-pruned vs uniform best ---
        const float HC2 = HC * HC;
        float bestU = best;                         // uniform after reduce
        #pragma unroll
        for (int dz = -1; dz <= 1; dz++) {
            int iz = cz + dz;
            if (iz < 0 || iz >= G) continue;        // uniform
            float dzl = (dz == 0) ? 0.f : ((dz > 0) ? (1.f - fz) : fz);
            #pragma unroll
            for (int dy = -1; dy <= 1; dy++) {
                int iy = cy + dy;
                if (iy < 0 || iy >= G) continue;
                int rowb = base + (iz * G + iy) * G;
                if (dz == 0 && dy == 0) {           // home row: two end cells
                    if (cx - 1 >= 0 && fx * fx * HC2 < bestU) {
                        int c0 = rowb + cx - 1;
                        int lo = c0 ? offc[c0 - 1] : 0;
                        int hi = offc[c0];
                        SCAN_RANGE(lo, hi)
                    }
                    if (cx + 1 < G && (1.f - fx) * (1.f - fx) * HC2 < bestU) {
                        int c0 = rowb + cx + 1;
                        int lo = c0 ? offc[c0 - 1] : 0;
                        int hi = offc[c0];
                        SCAN_RANGE(lo, hi)
                    }
                } else {                             // full row of 2-3 cells
                    float dyl = (dy == 0) ? 0.f : ((dy > 0) ? (1.f - fy) : fy);
                    if ((dzl * dzl + dyl * dyl) * HC2 < bestU) {
                        int c0 = rowb + max(cx - 1, 0);
                        int c1 = rowb + min(cx + 1, G - 1);
                        int lo = c0 ? offc[c0 - 1] : 0;
                        int hi = offc[c1];
                        SCAN_RANGE(lo, hi)
                    }
                }
            }
        }
        WAVE_MIN(best)
        float bnd1 = (1.0f + m) * HC;
        if (best > bnd1 * bnd1) {
            // --- rare: generic shells from s=2 (verbatim round 8) ---
            for (int s = 2; s <= G; ++s) {
                int zlo = max(cz - s, 0), zhi = min(cz + s, G - 1);
                for (int iz = zlo; iz <= zhi; ++iz) {
                    int adz = iz - cz; adz = (adz < 0) ? -adz : adz;
                    int ylo = max(cy - s, 0), yhi = min(cy + s, G - 1);
                    for (int iy = ylo; iy <= yhi; ++iy) {
                        int ady = iy - cy; ady = (ady < 0) ? -ady : ady;
                        int rowb = base + (iz * G + iy) * G;
                        if (adz == s || ady == s) {
                            int c0 = rowb + max(cx - s, 0);
                            int c1 = rowb + min(cx + s, G - 1);
                            int lo = c0 ? offc[c0 - 1] : 0;
                            int hi = offc[c1];
                            SCAN_RANGE(lo, hi)
                        } else {
                            if (cx - s >= 0) {
                                int c0 = rowb + cx - s;
                                int lo = c0 ? offc[c0 - 1] : 0;
                                int hi = offc[c0];
                                SCAN_RANGE(lo, hi)
                            }
                            if (cx + s <= G - 1) {
                                int c0 = rowb + cx + s;
                                int lo = c0 ? offc[c0 - 1] : 0;
                                int hi = offc[c0];
                                SCAN_RANGE(lo, hi)
                            }
                        }
                    }
                }
                WAVE_MIN(best)
                float bnd = ((float)s + m) * HC;
                if (best <= bnd * bnd) break;
            }
        }
    }

    if (lane == 0) pts[g].w = best;   // readers consume xyz only
}

// deterministic sum of pts[*].w
__global__ __launch_bounds__(256) void reduce1(
    const float4* __restrict__ pts, float* __restrict__ partials)
{
    int tid = threadIdx.x;
    int basei = blockIdx.x * 1024;
    float s = 0.f;
    #pragma unroll
    for (int t = 0; t < 4; t++) s += pts[basei + t * 256 + tid].w;
    #pragma unroll
    for (int o = 32; o; o >>= 1) s += __shfl_xor(s, o, 64);
    __shared__ float wsum[4];
    if ((tid & 63) == 0) wsum[tid >> 6] = s;
    __syncthreads();
    if (tid == 0) partials[blockIdx.x] = wsum[0] + wsum[1] + wsum[2] + wsum[3];
}

__global__ __launch_bounds__(256) void reduce2(
    const float* __restrict__ partials, float* __restrict__ out)
{
    int tid = threadIdx.x;
    float s = 0.f;
    for (int i = tid; i < 288; i += 256) s += partials[i];
    #pragma unroll
    for (int o = 32; o; o >>= 1) s += __shfl_xor(s, o, 64);
    __shared__ float wsum[4];
    if ((tid & 63) == 0) wsum[tid >> 6] = s;
    __syncthreads();
    if (tid == 0) out[0] = (wsum[0] + wsum[1] + wsum[2] + wsum[3]) / 147456.0f;
}

extern "C" void kernel_launch(void* const* d_in, const int* in_sizes, int n_in,
                              void* d_out, int out_size, void* d_ws, size_t ws_size,
                              hipStream_t stream) {
    const float* fake = (const float*)d_in[0];
    const float* tar  = (const float*)d_in[1];
    const int*   sh_p = (const int*)d_in[2];
    const int*   sw_p = (const int*)d_in[3];
    float* out = (float*)d_out;

    // ws layout identical to passing rounds 7/8: 5.35 MB total
    int* wsi = (int*)d_ws;
    int*    offc  = wsi;                        // NCI ints
    int*    bsum  = wsi + NCI;                  // 1024 ints
    float*  parts = (float*)(wsi + NCI + 1024); // 288 floats
    float4* pts   = (float4*)(wsi + NCI + 1312);// N2 float4, 16B-aligned

    zero_kernel<<<SCAN_BLOCKS, 256, 0, stream>>>(offc);
    count_kernel<<<N2 / 256, 256, 0, stream>>>(fake, tar, sh_p, sw_p, offc);
    scan1_kernel<<<SCAN_BLOCKS, 256, 0, stream>>>(offc, bsum);
    scan2_kernel<<<1, 1024, 0, stream>>>(bsum);
    scan3_kernel<<<SCAN_BLOCKS, 256, 0, stream>>>(offc, bsum);
    fill_kernel<<<N2 / 256, 256, 0, stream>>>(fake, tar, sh_p, sw_p, offc, pts);
    query_kernel<<<N2 / 4, 256, 0, stream>>>(pts, offc);   // one wave per query
    reduce1<<<N2 / 1024, 256, 0, stream>>>(pts, parts);
    reduce2<<<1, 256, 0, stream>>>(parts, out);
}